// Round 2
// baseline (3294.564 us; speedup 1.0000x reference)
//
#include <hip/hip_runtime.h>

#define IN_C 128
#define NF 4

// ---------------------------------------------------------------- utilities
__global__ void zero_ints(int* p, int n) {
    int i = blockIdx.x * 256 + threadIdx.x;
    if (i < n) p[i] = 0;
}

__global__ void count_deg(const int* __restrict__ ei, int* __restrict__ degr,
                          int* __restrict__ cnt, int E) {
    int e = blockIdx.x * 256 + threadIdx.x;
    if (e >= E) return;
    int r = ei[e];
    int c = ei[E + e];
    atomicAdd(&degr[r], 1);
    atomicAdd(&cnt[c], 1);
}

__global__ void dinv_k(const int* __restrict__ degr, float* __restrict__ dinv, int N) {
    int i = blockIdx.x * 256 + threadIdx.x;
    if (i >= N) return;
    int d = degr[i];
    dinv[i] = (d > 0) ? rsqrtf((float)d) : 0.0f;
}

// exclusive scan: per-block prescan + block totals
__global__ void scanA(const int* __restrict__ in, int* __restrict__ outp,
                      int* __restrict__ partials, int n) {
    __shared__ int tmp[256];
    int t = threadIdx.x;
    int gid = blockIdx.x * 256 + t;
    int v = (gid < n) ? in[gid] : 0;
    tmp[t] = v;
    __syncthreads();
    for (int off = 1; off < 256; off <<= 1) {
        int add = (t >= off) ? tmp[t - off] : 0;
        __syncthreads();
        tmp[t] += add;
        __syncthreads();
    }
    if (gid < n) outp[gid] = tmp[t] - v;   // exclusive within block
    if (t == 255) partials[blockIdx.x] = tmp[255];
}

__global__ void scanB(int* partials, int n) {  // n <= 256
    __shared__ int tmp[256];
    int t = threadIdx.x;
    int v = (t < n) ? partials[t] : 0;
    tmp[t] = v;
    __syncthreads();
    for (int off = 1; off < 256; off <<= 1) {
        int add = (t >= off) ? tmp[t - off] : 0;
        __syncthreads();
        tmp[t] += add;
        __syncthreads();
    }
    if (t < n) partials[t] = tmp[t] - v;   // exclusive
}

__global__ void scanC(int* __restrict__ offs, const int* __restrict__ partials,
                      int n, int total) {
    int gid = blockIdx.x * 256 + threadIdx.x;
    if (gid < n) offs[gid] += partials[blockIdx.x];
    if (gid == 0) offs[n] = total;
}

__global__ void fill_csr(const int* __restrict__ ei, const float* __restrict__ dinv,
                         const int* __restrict__ offs, int* __restrict__ cursor,
                         uint2* __restrict__ csr, int E) {
    int e = blockIdx.x * 256 + threadIdx.x;
    if (e >= E) return;
    int r = ei[e];
    int c = ei[E + e];
    float w = -dinv[r] * dinv[c] - 1.0f;   // (lap_w) - 1 ; appended self-loops become 0 -> dropped
    int pos = offs[c] + atomicAdd(&cursor[c], 1);
    csr[pos] = make_uint2((unsigned)r, __float_as_uint(w));
}

// ------------------------------------------------- propagation: C = alpha*(S A) - B
// one wave per dst node; lane holds 2 channels (float2)
__global__ __launch_bounds__(256) void propagate(
    const uint2* __restrict__ csr, const int* __restrict__ offs,
    const float* __restrict__ A, const float* __restrict__ Bsub,
    float* __restrict__ C, float alpha, int N)
{
    int node = blockIdx.x * 4 + (threadIdx.x >> 6);
    int lane = threadIdx.x & 63;
    if (node >= N) return;
    int beg = offs[node];
    int end = offs[node + 1];
    float sx = 0.f, sy = 0.f;
    for (int j = beg; j < end; ++j) {
        uint2 e = csr[j];
        int src = (int)e.x;
        float w = __uint_as_float(e.y);
        float2 v = ((const float2*)(A + (size_t)src * IN_C))[lane];
        sx += w * v.x;
        sy += w * v.y;
    }
    float ox, oy;
    if (Bsub) {
        float2 b = ((const float2*)(Bsub + (size_t)node * IN_C))[lane];
        ox = alpha * sx - b.x;
        oy = alpha * sy - b.y;
    } else {
        ox = alpha * sx;
        oy = alpha * sy;
    }
    float2 o; o.x = ox; o.y = oy;
    ((float2*)(C + (size_t)node * IN_C))[lane] = o;
}

// ------------------------------------------------- GEMM-accumulate:
// for each active filter f (blockIdx.y): acc_f += T_k @ W[5*f*(f+1)/2 + k]
// 128x128 block tile, 8x8 per-thread microtile, K chunked by 32 through LDS.
__global__ __launch_bounds__(256) void gemm_acc(
    const float* __restrict__ T, const float* __restrict__ cheb_w,
    float* __restrict__ acc_base, int N, int k, int i0, int beta)
{
    __shared__ float Wl[32 * 132];
    __shared__ float Tl[128 * 36];
    int f = i0 + blockIdx.y;
    int gk = (5 * f * (f + 1)) / 2 + k;
    const float* __restrict__ W = cheb_w + (size_t)gk * (128 * 128);
    float* __restrict__ acc = acc_base + (size_t)f * N * 128;
    int r0 = blockIdx.x * 128;
    int tid = threadIdx.x;
    int tx = tid & 15;    // col group: cols tx*8 .. tx*8+7
    int ty = tid >> 4;    // row group: rows r0+ty*8 .. +7

    float racc[8][8];
#pragma unroll
    for (int i = 0; i < 8; ++i)
#pragma unroll
        for (int c = 0; c < 8; ++c) racc[i][c] = 0.f;

    for (int kc = 0; kc < 4; ++kc) {
        // stage W rows [kc*32, kc*32+32) x 128 cols
#pragma unroll
        for (int j = 0; j < 4; ++j) {
            int lin = (tid + j * 256) * 4;          // 0..4095 elements
            int kk = lin >> 7;
            int c = lin & 127;
            float4 v = *(const float4*)(W + (size_t)(kc * 32 + kk) * 128 + c);
            *(float4*)(&Wl[kk * 132 + c]) = v;
        }
        // stage T rows [r0, r0+128) x K cols [kc*32, kc*32+32)
#pragma unroll
        for (int j = 0; j < 4; ++j) {
            int lin = (tid + j * 256) * 4;
            int r = lin >> 5;
            int kkk = lin & 31;
            int row = r0 + r;
            float4 v = make_float4(0.f, 0.f, 0.f, 0.f);
            if (row < N) v = *(const float4*)(T + (size_t)row * 128 + kc * 32 + kkk);
            *(float4*)(&Tl[r * 36 + kkk]) = v;
        }
        __syncthreads();
#pragma unroll
        for (int kk = 0; kk < 32; kk += 4) {
            float4 tv[8];
#pragma unroll
            for (int i = 0; i < 8; ++i)
                tv[i] = *(const float4*)(&Tl[(ty * 8 + i) * 36 + kk]);
            float4 wv0[4], wv1[4];
#pragma unroll
            for (int q = 0; q < 4; ++q) {
                wv0[q] = *(const float4*)(&Wl[(kk + q) * 132 + tx * 8]);
                wv1[q] = *(const float4*)(&Wl[(kk + q) * 132 + tx * 8 + 4]);
            }
#pragma unroll
            for (int q = 0; q < 4; ++q) {
#pragma unroll
                for (int i = 0; i < 8; ++i) {
                    float t = (q == 0) ? tv[i].x : (q == 1) ? tv[i].y : (q == 2) ? tv[i].z : tv[i].w;
                    racc[i][0] += t * wv0[q].x;
                    racc[i][1] += t * wv0[q].y;
                    racc[i][2] += t * wv0[q].z;
                    racc[i][3] += t * wv0[q].w;
                    racc[i][4] += t * wv1[q].x;
                    racc[i][5] += t * wv1[q].y;
                    racc[i][6] += t * wv1[q].z;
                    racc[i][7] += t * wv1[q].w;
                }
            }
        }
        __syncthreads();
    }
    // epilogue: acc = beta*acc + racc
#pragma unroll
    for (int i = 0; i < 8; ++i) {
        int row = r0 + ty * 8 + i;
        if (row >= N) continue;
        float* p = acc + (size_t)row * 128 + tx * 8;
        float4 o0 = make_float4(racc[i][0], racc[i][1], racc[i][2], racc[i][3]);
        float4 o1 = make_float4(racc[i][4], racc[i][5], racc[i][6], racc[i][7]);
        if (beta) {
            float4 a0 = *(const float4*)p;
            float4 a1 = *(const float4*)(p + 4);
            o0.x += a0.x; o0.y += a0.y; o0.z += a0.z; o0.w += a0.w;
            o1.x += a1.x; o1.y += a1.y; o1.z += a1.z; o1.w += a1.w;
        }
        *(float4*)p = o0;
        *(float4*)(p + 4) = o1;
    }
}

// ------------------------------------------------- attention + scale-safe LayerNorm
__global__ __launch_bounds__(256) void attn_ln(
    const float* __restrict__ acc_base, const float* __restrict__ cheb_b,
    const float* __restrict__ attn_w, const float* __restrict__ attn_b,
    const float* __restrict__ ln_g, const float* __restrict__ ln_b,
    float* __restrict__ out, int N)
{
    int node = blockIdx.x * 4 + (threadIdx.x >> 6);
    int lane = threadIdx.x & 63;
    if (node >= N) return;
    int c = lane * 2;

    float2 o[NF];
#pragma unroll
    for (int f = 0; f < NF; ++f) {
        float2 v = ((const float2*)(acc_base + (size_t)f * N * 128 + (size_t)node * 128))[lane];
        v.x += cheb_b[f * 128 + c];
        v.y += cheb_b[f * 128 + c + 1];
        o[f] = v;
    }
    // logits: feats @ attn_w + attn_b   (attn_w is (512,4) row-major)
    float l0 = 0.f, l1 = 0.f, l2 = 0.f, l3 = 0.f;
#pragma unroll
    for (int fi = 0; fi < NF; ++fi) {
        const float* aw = attn_w + (size_t)(fi * 128 + c) * 4;
        l0 += o[fi].x * aw[0] + o[fi].y * aw[4];
        l1 += o[fi].x * aw[1] + o[fi].y * aw[5];
        l2 += o[fi].x * aw[2] + o[fi].y * aw[6];
        l3 += o[fi].x * aw[3] + o[fi].y * aw[7];
    }
#pragma unroll
    for (int off = 32; off; off >>= 1) {
        l0 += __shfl_xor(l0, off);
        l1 += __shfl_xor(l1, off);
        l2 += __shfl_xor(l2, off);
        l3 += __shfl_xor(l3, off);
    }
    l0 += attn_b[0]; l1 += attn_b[1]; l2 += attn_b[2]; l3 += attn_b[3];
    float m = fmaxf(fmaxf(l0, l1), fmaxf(l2, l3));
    float e0 = expf(l0 - m), e1 = expf(l1 - m), e2 = expf(l2 - m), e3 = expf(l3 - m);
    float inv_s = 1.f / (e0 + e1 + e2 + e3);
    float p0 = e0 * inv_s, p1 = e1 * inv_s, p2 = e2 * inv_s, p3 = e3 * inv_s;

    float cx = p0 * o[0].x + p1 * o[1].x + p2 * o[2].x + p3 * o[3].x;
    float cy = p0 * o[0].y + p1 * o[1].y + p2 * o[2].y + p3 * o[3].y;

    // mean
    float sum = cx + cy;
#pragma unroll
    for (int off = 32; off; off >>= 1) sum += __shfl_xor(sum, off);
    float mu = sum * (1.f / 128.f);
    float dx = cx - mu, dy = cy - mu;

    // scale-invariant variance: avoid fp32 overflow of d^2 for huge activations
    float M = fmaxf(fabsf(dx), fabsf(dy));
#pragma unroll
    for (int off = 32; off; off >>= 1) M = fmaxf(M, __shfl_xor(M, off));

    float zx, zy, r;
    if (M > 0.f) {
        float inv = 1.f / M;
        zx = dx * inv;
        zy = dy * inv;
        float v2 = zx * zx + zy * zy;
#pragma unroll
        for (int off = 32; off; off >>= 1) v2 += __shfl_xor(v2, off);
        float var = v2 * (1.f / 128.f);
        r = rsqrtf(var + 1e-5f * inv * inv);   // == rsqrt(var_true + eps), scale-free
    } else {
        zx = 0.f; zy = 0.f; r = 0.f;
    }
    out[(size_t)node * 128 + c]     = zx * r * ln_g[c]     + ln_b[c];
    out[(size_t)node * 128 + c + 1] = zy * r * ln_g[c + 1] + ln_b[c + 1];
}

// ---------------------------------------------------------------- launch
extern "C" void kernel_launch(void* const* d_in, const int* in_sizes, int n_in,
                              void* d_out, int out_size, void* d_ws, size_t ws_size,
                              hipStream_t stream) {
    const float* x       = (const float*)d_in[0];
    const int* ei        = (const int*)d_in[1];     // int32! jax x64-disabled downgrades int64
    const float* cheb_w  = (const float*)d_in[2];
    const float* cheb_b  = (const float*)d_in[3];
    const float* attn_w  = (const float*)d_in[4];
    const float* attn_b  = (const float*)d_in[5];
    const float* ln_g    = (const float*)d_in[6];
    const float* ln_b    = (const float*)d_in[7];
    float* out = (float*)d_out;

    int N = in_sizes[0] / 128;
    int E = in_sizes[1] / 2;

    char* w = (char*)d_ws;
    auto alloc = [&](size_t bytes) -> void* {
        void* p = (void*)w;
        w += (bytes + 255) & ~(size_t)255;
        return p;
    };
    size_t mat_bytes = (size_t)N * 128 * sizeof(float);
    float* Tb[3];
    for (int i = 0; i < 3; ++i) Tb[i] = (float*)alloc(mat_bytes);
    float* acc   = (float*)alloc(4 * mat_bytes);
    uint2* csr   = (uint2*)alloc((size_t)E * sizeof(uint2));
    int* offs    = (int*)alloc((size_t)(N + 1) * sizeof(int));
    int* zero3   = (int*)alloc((size_t)3 * N * sizeof(int));
    int* degr = zero3, *cnt = zero3 + N, *cursor = zero3 + 2 * N;
    float* dinv  = (float*)alloc((size_t)N * sizeof(float));
    int* partials = (int*)alloc(1024 * sizeof(int));
    if ((size_t)(w - (char*)d_ws) > ws_size) return;  // workspace too small

    int eb = (E + 255) / 256;
    int nb = (N + 255) / 256;

    zero_ints<<<(3 * N + 255) / 256, 256, 0, stream>>>(zero3, 3 * N);
    count_deg<<<eb, 256, 0, stream>>>(ei, degr, cnt, E);
    dinv_k<<<nb, 256, 0, stream>>>(degr, dinv, N);
    scanA<<<nb, 256, 0, stream>>>(cnt, offs, partials, N);
    scanB<<<1, 256, 0, stream>>>(partials, nb);
    scanC<<<nb, 256, 0, stream>>>(offs, partials, N, E);
    fill_csr<<<eb, 256, 0, stream>>>(ei, dinv, offs, cursor, csr, E);

    int rtiles = (N + 127) / 128;
    // k = 0: acc_f = x @ W_f0  (beta=0 initializes)
    {
        dim3 g(rtiles, 4);
        gemm_acc<<<g, 256, 0, stream>>>(x, cheb_w, acc, N, 0, 0, 0);
    }
    int pb = (N + 3) / 4;
    for (int k = 1; k < 20; ++k) {
        const float* A = (k == 1) ? x : Tb[(k - 2) % 3];
        const float* B = (k == 1) ? nullptr : ((k == 2) ? x : Tb[(k - 3) % 3]);
        float* C = Tb[(k - 1) % 3];
        propagate<<<pb, 256, 0, stream>>>(csr, offs, A, B, C, (k == 1) ? 1.f : 2.f, N);
        int i0 = (k < 5) ? 0 : (k < 10) ? 1 : (k < 15) ? 2 : 3;
        dim3 g(rtiles, 4 - i0);
        gemm_acc<<<g, 256, 0, stream>>>(C, cheb_w, acc, N, k, i0, 1);
    }
    attn_ln<<<pb, 256, 0, stream>>>(acc, cheb_b, attn_w, attn_b, ln_g, ln_b, out, N);
}

// Round 3
// 2997.060 us; speedup vs baseline: 1.0993x; 1.0993x over previous
//
#include <hip/hip_runtime.h>

#define IN_C 128
#define NF 4

// ---------------------------------------------------------------- utilities
__global__ void zero_ints(int* p, int n) {
    int i = blockIdx.x * 256 + threadIdx.x;
    if (i < n) p[i] = 0;
}

__global__ void count_deg(const int* __restrict__ ei, int* __restrict__ degr,
                          int* __restrict__ cnt, int E) {
    int e = blockIdx.x * 256 + threadIdx.x;
    if (e >= E) return;
    int r = ei[e];
    int c = ei[E + e];
    atomicAdd(&degr[r], 1);
    atomicAdd(&cnt[c], 1);
}

__global__ void dinv_k(const int* __restrict__ degr, float* __restrict__ dinv, int N) {
    int i = blockIdx.x * 256 + threadIdx.x;
    if (i >= N) return;
    int d = degr[i];
    dinv[i] = (d > 0) ? rsqrtf((float)d) : 0.0f;
}

// exclusive scan: per-block prescan + block totals
__global__ void scanA(const int* __restrict__ in, int* __restrict__ outp,
                      int* __restrict__ partials, int n) {
    __shared__ int tmp[256];
    int t = threadIdx.x;
    int gid = blockIdx.x * 256 + t;
    int v = (gid < n) ? in[gid] : 0;
    tmp[t] = v;
    __syncthreads();
    for (int off = 1; off < 256; off <<= 1) {
        int add = (t >= off) ? tmp[t - off] : 0;
        __syncthreads();
        tmp[t] += add;
        __syncthreads();
    }
    if (gid < n) outp[gid] = tmp[t] - v;   // exclusive within block
    if (t == 255) partials[blockIdx.x] = tmp[255];
}

__global__ void scanB(int* partials, int n) {  // n <= 256
    __shared__ int tmp[256];
    int t = threadIdx.x;
    int v = (t < n) ? partials[t] : 0;
    tmp[t] = v;
    __syncthreads();
    for (int off = 1; off < 256; off <<= 1) {
        int add = (t >= off) ? tmp[t - off] : 0;
        __syncthreads();
        tmp[t] += add;
        __syncthreads();
    }
    if (t < n) partials[t] = tmp[t] - v;   // exclusive
}

__global__ void scanC(int* __restrict__ offs, const int* __restrict__ partials,
                      int n, int total) {
    int gid = blockIdx.x * 256 + threadIdx.x;
    if (gid < n) offs[gid] += partials[blockIdx.x];
    if (gid == 0) offs[n] = total;
}

__global__ void fill_csr(const int* __restrict__ ei, const float* __restrict__ dinv,
                         const int* __restrict__ offs, int* __restrict__ cursor,
                         uint2* __restrict__ csr, int E) {
    int e = blockIdx.x * 256 + threadIdx.x;
    if (e >= E) return;
    int r = ei[e];
    int c = ei[E + e];
    float w = -dinv[r] * dinv[c] - 1.0f;   // (lap_w) - 1 ; appended self-loops become 0 -> dropped
    int pos = offs[c] + atomicAdd(&cursor[c], 1);
    csr[pos] = make_uint2((unsigned)r, __float_as_uint(w));
}

// ------------------------------------------------- propagation: C = alpha*(S A) - B
// one wave per dst node; lane holds 2 channels (float2)
__global__ __launch_bounds__(256) void propagate(
    const uint2* __restrict__ csr, const int* __restrict__ offs,
    const float* __restrict__ A, const float* __restrict__ Bsub,
    float* __restrict__ C, float alpha, int N)
{
    int node = blockIdx.x * 4 + (threadIdx.x >> 6);
    int lane = threadIdx.x & 63;
    if (node >= N) return;
    int beg = offs[node];
    int end = offs[node + 1];
    float sx = 0.f, sy = 0.f;
    for (int j = beg; j < end; ++j) {
        uint2 e = csr[j];
        int src = (int)e.x;
        float w = __uint_as_float(e.y);
        float2 v = ((const float2*)(A + (size_t)src * IN_C))[lane];
        sx += w * v.x;
        sy += w * v.y;
    }
    float ox, oy;
    if (Bsub) {
        float2 b = ((const float2*)(Bsub + (size_t)node * IN_C))[lane];
        ox = alpha * sx - b.x;
        oy = alpha * sy - b.y;
    } else {
        ox = alpha * sx;
        oy = alpha * sy;
    }
    float2 o; o.x = ox; o.y = oy;
    ((float2*)(C + (size_t)node * IN_C))[lane] = o;
}

// ------------------------------------------------- grouped GEMM-accumulate
// Group g covers k = 5g .. 5g+4 (all 5 used by every active filter since
// K_f = 5(f+1)). blockIdx.y enumerates active filters f = g + blockIdx.y.
// acc_f (+)= sum_{kl=0..4} T_{5g+kl} @ W[off_f + 5g + kl]
// Register accumulation across the whole K=640; acc hits HBM once per group.
__global__ __launch_bounds__(256) void gemm_group(
    const float* __restrict__ x, const float* __restrict__ slots,
    const float* __restrict__ cheb_w, float* __restrict__ acc_base,
    int N, int g)
{
    __shared__ float Wl[32 * 132];
    __shared__ float Tl[128 * 36];
    int f = g + blockIdx.y;
    const float* __restrict__ Wbase = cheb_w + (size_t)((5 * f * (f + 1)) / 2 + 5 * g) * (128 * 128);
    float* __restrict__ acc = acc_base + (size_t)f * N * 128;
    int r0 = blockIdx.x * 128;
    int tid = threadIdx.x;
    int tx = tid & 15;    // col group: cols tx*8 .. tx*8+7
    int ty = tid >> 4;    // row group: rows r0+ty*8 .. +7

    float racc[8][8];
#pragma unroll
    for (int i = 0; i < 8; ++i)
#pragma unroll
        for (int c = 0; c < 8; ++c) racc[i][c] = 0.f;

    for (int t = 0; t < 20; ++t) {
        int kl = t >> 2;    // local k 0..4  (slot index == kl since 5g % 5 == 0)
        int kc = t & 3;     // 32-wide K chunk within the 128
        const float* __restrict__ W = Wbase + (size_t)kl * (128 * 128);
        const float* __restrict__ T = (g == 0 && kl == 0) ? x
                                     : slots + (size_t)kl * N * 128;
        // stage W rows [kc*32, +32) x 128 cols
#pragma unroll
        for (int j = 0; j < 4; ++j) {
            int lin = (tid + j * 256) * 4;          // 0..4095 elements
            int kk = lin >> 7;
            int c = lin & 127;
            float4 v = *(const float4*)(W + (size_t)(kc * 32 + kk) * 128 + c);
            *(float4*)(&Wl[kk * 132 + c]) = v;
        }
        // stage T rows [r0, r0+128) x K cols [kc*32, +32)
#pragma unroll
        for (int j = 0; j < 4; ++j) {
            int lin = (tid + j * 256) * 4;
            int r = lin >> 5;
            int kkk = lin & 31;
            int row = r0 + r;
            float4 v = make_float4(0.f, 0.f, 0.f, 0.f);
            if (row < N) v = *(const float4*)(T + (size_t)row * 128 + kc * 32 + kkk);
            *(float4*)(&Tl[r * 36 + kkk]) = v;
        }
        __syncthreads();
#pragma unroll
        for (int kk = 0; kk < 32; kk += 4) {
            float4 tv[8];
#pragma unroll
            for (int i = 0; i < 8; ++i)
                tv[i] = *(const float4*)(&Tl[(ty * 8 + i) * 36 + kk]);
            float4 wv0[4], wv1[4];
#pragma unroll
            for (int q = 0; q < 4; ++q) {
                wv0[q] = *(const float4*)(&Wl[(kk + q) * 132 + tx * 8]);
                wv1[q] = *(const float4*)(&Wl[(kk + q) * 132 + tx * 8 + 4]);
            }
#pragma unroll
            for (int q = 0; q < 4; ++q) {
#pragma unroll
                for (int i = 0; i < 8; ++i) {
                    float t2 = (q == 0) ? tv[i].x : (q == 1) ? tv[i].y : (q == 2) ? tv[i].z : tv[i].w;
                    racc[i][0] += t2 * wv0[q].x;
                    racc[i][1] += t2 * wv0[q].y;
                    racc[i][2] += t2 * wv0[q].z;
                    racc[i][3] += t2 * wv0[q].w;
                    racc[i][4] += t2 * wv1[q].x;
                    racc[i][5] += t2 * wv1[q].y;
                    racc[i][6] += t2 * wv1[q].z;
                    racc[i][7] += t2 * wv1[q].w;
                }
            }
        }
        __syncthreads();
    }
    // epilogue: acc = (g>0 ? acc : 0) + racc
    int beta = (g > 0);
#pragma unroll
    for (int i = 0; i < 8; ++i) {
        int row = r0 + ty * 8 + i;
        if (row >= N) continue;
        float* p = acc + (size_t)row * 128 + tx * 8;
        float4 o0 = make_float4(racc[i][0], racc[i][1], racc[i][2], racc[i][3]);
        float4 o1 = make_float4(racc[i][4], racc[i][5], racc[i][6], racc[i][7]);
        if (beta) {
            float4 a0 = *(const float4*)p;
            float4 a1 = *(const float4*)(p + 4);
            o0.x += a0.x; o0.y += a0.y; o0.z += a0.z; o0.w += a0.w;
            o1.x += a1.x; o1.y += a1.y; o1.z += a1.z; o1.w += a1.w;
        }
        *(float4*)p = o0;
        *(float4*)(p + 4) = o1;
    }
}

// ------------------------------------------------- attention + scale-safe LayerNorm
__global__ __launch_bounds__(256) void attn_ln(
    const float* __restrict__ acc_base, const float* __restrict__ cheb_b,
    const float* __restrict__ attn_w, const float* __restrict__ attn_b,
    const float* __restrict__ ln_g, const float* __restrict__ ln_b,
    float* __restrict__ out, int N)
{
    int node = blockIdx.x * 4 + (threadIdx.x >> 6);
    int lane = threadIdx.x & 63;
    if (node >= N) return;
    int c = lane * 2;

    float2 o[NF];
#pragma unroll
    for (int f = 0; f < NF; ++f) {
        float2 v = ((const float2*)(acc_base + (size_t)f * N * 128 + (size_t)node * 128))[lane];
        v.x += cheb_b[f * 128 + c];
        v.y += cheb_b[f * 128 + c + 1];
        o[f] = v;
    }
    // logits: feats @ attn_w + attn_b   (attn_w is (512,4) row-major)
    float l0 = 0.f, l1 = 0.f, l2 = 0.f, l3 = 0.f;
#pragma unroll
    for (int fi = 0; fi < NF; ++fi) {
        const float* aw = attn_w + (size_t)(fi * 128 + c) * 4;
        l0 += o[fi].x * aw[0] + o[fi].y * aw[4];
        l1 += o[fi].x * aw[1] + o[fi].y * aw[5];
        l2 += o[fi].x * aw[2] + o[fi].y * aw[6];
        l3 += o[fi].x * aw[3] + o[fi].y * aw[7];
    }
#pragma unroll
    for (int off = 32; off; off >>= 1) {
        l0 += __shfl_xor(l0, off);
        l1 += __shfl_xor(l1, off);
        l2 += __shfl_xor(l2, off);
        l3 += __shfl_xor(l3, off);
    }
    l0 += attn_b[0]; l1 += attn_b[1]; l2 += attn_b[2]; l3 += attn_b[3];
    float m = fmaxf(fmaxf(l0, l1), fmaxf(l2, l3));
    float e0 = expf(l0 - m), e1 = expf(l1 - m), e2 = expf(l2 - m), e3 = expf(l3 - m);
    float inv_s = 1.f / (e0 + e1 + e2 + e3);
    float p0 = e0 * inv_s, p1 = e1 * inv_s, p2 = e2 * inv_s, p3 = e3 * inv_s;

    float cx = p0 * o[0].x + p1 * o[1].x + p2 * o[2].x + p3 * o[3].x;
    float cy = p0 * o[0].y + p1 * o[1].y + p2 * o[2].y + p3 * o[3].y;

    // mean
    float sum = cx + cy;
#pragma unroll
    for (int off = 32; off; off >>= 1) sum += __shfl_xor(sum, off);
    float mu = sum * (1.f / 128.f);
    float dx = cx - mu, dy = cy - mu;

    // scale-invariant variance: avoid fp32 overflow of d^2 for huge activations
    float M = fmaxf(fabsf(dx), fabsf(dy));
#pragma unroll
    for (int off = 32; off; off >>= 1) M = fmaxf(M, __shfl_xor(M, off));

    float zx, zy, r;
    if (M > 0.f) {
        float inv = 1.f / M;
        zx = dx * inv;
        zy = dy * inv;
        float v2 = zx * zx + zy * zy;
#pragma unroll
        for (int off = 32; off; off >>= 1) v2 += __shfl_xor(v2, off);
        float var = v2 * (1.f / 128.f);
        r = rsqrtf(var + 1e-5f * inv * inv);   // == rsqrt(var_true + eps), scale-free
    } else {
        zx = 0.f; zy = 0.f; r = 0.f;
    }
    out[(size_t)node * 128 + c]     = zx * r * ln_g[c]     + ln_b[c];
    out[(size_t)node * 128 + c + 1] = zy * r * ln_g[c + 1] + ln_b[c + 1];
}

// ---------------------------------------------------------------- launch
extern "C" void kernel_launch(void* const* d_in, const int* in_sizes, int n_in,
                              void* d_out, int out_size, void* d_ws, size_t ws_size,
                              hipStream_t stream) {
    const float* x       = (const float*)d_in[0];
    const int* ei        = (const int*)d_in[1];     // int32 (jax x64-disabled)
    const float* cheb_w  = (const float*)d_in[2];
    const float* cheb_b  = (const float*)d_in[3];
    const float* attn_w  = (const float*)d_in[4];
    const float* attn_b  = (const float*)d_in[5];
    const float* ln_g    = (const float*)d_in[6];
    const float* ln_b    = (const float*)d_in[7];
    float* out = (float*)d_out;

    int N = in_sizes[0] / 128;
    int E = in_sizes[1] / 2;

    char* w = (char*)d_ws;
    auto alloc = [&](size_t bytes) -> void* {
        void* p = (void*)w;
        w += (bytes + 255) & ~(size_t)255;
        return p;
    };
    size_t mat_bytes = (size_t)N * 128 * sizeof(float);
    float* slots = (float*)alloc(5 * mat_bytes);     // T_k lives in slot k%5
    float* acc   = (float*)alloc(4 * mat_bytes);
    uint2* csr   = (uint2*)alloc((size_t)E * sizeof(uint2));
    int* offs    = (int*)alloc((size_t)(N + 1) * sizeof(int));
    int* zero3   = (int*)alloc((size_t)3 * N * sizeof(int));
    int* degr = zero3, *cnt = zero3 + N, *cursor = zero3 + 2 * N;
    float* dinv  = (float*)alloc((size_t)N * sizeof(float));
    int* partials = (int*)alloc(1024 * sizeof(int));
    if ((size_t)(w - (char*)d_ws) > ws_size) return;  // workspace too small

    int eb = (E + 255) / 256;
    int nb = (N + 255) / 256;

    zero_ints<<<(3 * N + 255) / 256, 256, 0, stream>>>(zero3, 3 * N);
    count_deg<<<eb, 256, 0, stream>>>(ei, degr, cnt, E);
    dinv_k<<<nb, 256, 0, stream>>>(degr, dinv, N);
    scanA<<<nb, 256, 0, stream>>>(cnt, offs, partials, N);
    scanB<<<1, 256, 0, stream>>>(partials, nb);
    scanC<<<nb, 256, 0, stream>>>(offs, partials, N, E);
    fill_csr<<<eb, 256, 0, stream>>>(ei, dinv, offs, cursor, csr, E);

    int rtiles = (N + 127) / 128;
    int pb = (N + 3) / 4;
    size_t matf = (size_t)N * 128;

    for (int g = 0; g < 4; ++g) {
        // propagate T_k for k = 5g+? .. (skip k=0: T_0 == x)
        int kbeg = 5 * g + (g == 0 ? 1 : 0);
        int kend = 5 * g + 4;
        for (int k = kbeg; k <= kend; ++k) {
            const float* A = (k == 1) ? x : slots + (size_t)((k - 1) % 5) * matf;
            const float* B = (k == 1) ? nullptr
                            : ((k == 2) ? x : slots + (size_t)((k - 2) % 5) * matf);
            float* C = slots + (size_t)(k % 5) * matf;
            propagate<<<pb, 256, 0, stream>>>(csr, offs, A, B, C, (k == 1) ? 1.f : 2.f, N);
        }
        dim3 grid(rtiles, 4 - g);
        gemm_group<<<grid, 256, 0, stream>>>(x, slots, cheb_w, acc, N, g);
    }
    attn_ln<<<pb, 256, 0, stream>>>(acc, cheb_b, attn_w, attn_b, ln_g, ln_b, out, N);
}

// Round 4
// 1919.703 us; speedup vs baseline: 1.7162x; 1.5612x over previous
//
#include <hip/hip_runtime.h>

#define IN_C 128
#define NF 4

typedef __attribute__((ext_vector_type(8))) short short8;   // 8 bf16 (4 VGPRs)
typedef __attribute__((ext_vector_type(4))) float f32x4;    // MFMA C/D frag

__device__ __forceinline__ unsigned short f2bf(float v) {   // RNE float->bf16
    unsigned u = __float_as_uint(v);
    return (unsigned short)((u + 0x7fffu + ((u >> 16) & 1u)) >> 16);
}

// ---------------------------------------------------------------- utilities
__global__ void zero_ints(int* p, int n) {
    int i = blockIdx.x * 256 + threadIdx.x;
    if (i < n) p[i] = 0;
}

__global__ void count_deg(const int* __restrict__ ei, int* __restrict__ degr,
                          int* __restrict__ cnt, int E) {
    int e = blockIdx.x * 256 + threadIdx.x;
    if (e >= E) return;
    atomicAdd(&degr[ei[e]], 1);
    atomicAdd(&cnt[ei[E + e]], 1);
}

__global__ void dinv_k(const int* __restrict__ degr, float* __restrict__ dinv, int N) {
    int i = blockIdx.x * 256 + threadIdx.x;
    if (i >= N) return;
    int d = degr[i];
    dinv[i] = (d > 0) ? rsqrtf((float)d) : 0.0f;
}

__global__ void scanA(const int* __restrict__ in, int* __restrict__ outp,
                      int* __restrict__ partials, int n) {
    __shared__ int tmp[256];
    int t = threadIdx.x;
    int gid = blockIdx.x * 256 + t;
    int v = (gid < n) ? in[gid] : 0;
    tmp[t] = v;
    __syncthreads();
    for (int off = 1; off < 256; off <<= 1) {
        int add = (t >= off) ? tmp[t - off] : 0;
        __syncthreads();
        tmp[t] += add;
        __syncthreads();
    }
    if (gid < n) outp[gid] = tmp[t] - v;
    if (t == 255) partials[blockIdx.x] = tmp[255];
}

__global__ void scanB(int* partials, int n) {  // n <= 256
    __shared__ int tmp[256];
    int t = threadIdx.x;
    int v = (t < n) ? partials[t] : 0;
    tmp[t] = v;
    __syncthreads();
    for (int off = 1; off < 256; off <<= 1) {
        int add = (t >= off) ? tmp[t - off] : 0;
        __syncthreads();
        tmp[t] += add;
        __syncthreads();
    }
    if (t < n) partials[t] = tmp[t] - v;
}

__global__ void scanC(int* __restrict__ offs, const int* __restrict__ partials,
                      int n, int total) {
    int gid = blockIdx.x * 256 + threadIdx.x;
    if (gid < n) offs[gid] += partials[blockIdx.x];
    if (gid == 0) offs[n] = total;
}

__global__ void fill_csr(const int* __restrict__ ei, const float* __restrict__ dinv,
                         const int* __restrict__ offs, int* __restrict__ cursor,
                         uint2* __restrict__ csr, int E) {
    int e = blockIdx.x * 256 + threadIdx.x;
    if (e >= E) return;
    int r = ei[e];
    int c = ei[E + e];
    float w = -dinv[r] * dinv[c] - 1.0f;   // lap_w - 1 ; appended self-loops -> 0, dropped
    int pos = offs[c] + atomicAdd(&cursor[c], 1);
    csr[pos] = make_uint2((unsigned)r, __float_as_uint(w));
}

// ------------------------------------------------- one-time weight prep
// wht[gk][o][c] = bf16(cheb_w[gk][c][o])   (transposed for MFMA B-frag reads)
__global__ void wtr(const float* __restrict__ cheb_w, unsigned short* __restrict__ wht) {
    int gk = blockIdx.x;
    const float* src = cheb_w + (size_t)gk * 16384;
    unsigned short* dst = wht + (size_t)gk * 16384;
    for (int j = 0; j < 64; ++j) {
        int idx = threadIdx.x + j * 256;     // 0..16383, coalesced read
        int c = idx >> 7, o = idx & 127;
        dst[o * 128 + c] = f2bf(src[idx]);
    }
}

// V[k][c][j] = sum_{f: K_f > k} sum_o cheb_w[gk(f,k)][c][o] * attn_w[(f*128+o)*4 + j]
__global__ void vprep(const float* __restrict__ cheb_w, const float* __restrict__ attn_w,
                      float* __restrict__ V) {
    int k = blockIdx.x;      // 0..19
    int c = threadIdx.x;     // 0..127
    float s[4] = {0.f, 0.f, 0.f, 0.f};
    for (int f = k / 5; f < 4; ++f) {
        const float* wrow = cheb_w + (size_t)((5 * f * (f + 1)) / 2 + k) * 16384 + c * 128;
        const float* arow = attn_w + (size_t)f * 512;
        for (int o = 0; o < 128; ++o) {
            float wv = wrow[o];
            s[0] += wv * arow[o * 4 + 0];
            s[1] += wv * arow[o * 4 + 1];
            s[2] += wv * arow[o * 4 + 2];
            s[3] += wv * arow[o * 4 + 3];
        }
    }
    float* dst = V + k * 512 + c * 4;
    dst[0] = s[0]; dst[1] = s[1]; dst[2] = s[2]; dst[3] = s[3];
}

// constj[j] = sum_t cheb_b_flat[t] * attn_w[t*4+j] + attn_b[j]
__global__ void bias_const(const float* __restrict__ cheb_b, const float* __restrict__ attn_w,
                           const float* __restrict__ attn_b, float* __restrict__ constj) {
    int j = threadIdx.x;
    if (j >= 4) return;
    float s = attn_b[j];
    for (int t = 0; t < 512; ++t) s += cheb_b[t] * attn_w[t * 4 + j];
    constj[j] = s;
}

// logits[n][:] = x[n] . V_0 + constj  (wave per node)
__global__ __launch_bounds__(256) void logit_init(
    const float* __restrict__ x, const float* __restrict__ V,
    const float* __restrict__ constj, float* __restrict__ logits, int N)
{
    int node = blockIdx.x * 4 + (threadIdx.x >> 6);
    int lane = threadIdx.x & 63;
    if (node >= N) return;
    float2 v = ((const float2*)(x + (size_t)node * 128))[lane];
    int cc = lane * 2;
    float4 va = *(const float4*)(V + 4 * cc);
    float4 vb = *(const float4*)(V + 4 * cc + 4);
    float l0 = v.x * va.x + v.y * vb.x;
    float l1 = v.x * va.y + v.y * vb.y;
    float l2 = v.x * va.z + v.y * vb.z;
    float l3 = v.x * va.w + v.y * vb.w;
#pragma unroll
    for (int off = 32; off; off >>= 1) {
        l0 += __shfl_xor(l0, off); l1 += __shfl_xor(l1, off);
        l2 += __shfl_xor(l2, off); l3 += __shfl_xor(l3, off);
    }
    if (lane == 0) {
        float4 cj = *(const float4*)constj;
        *(float4*)(logits + 4 * node) =
            make_float4(l0 + cj.x, l1 + cj.y, l2 + cj.z, l3 + cj.w);
    }
}

// ------------------------------------------------- propagation: C = alpha*(S A) - B
// fused: logits[n][:] += C[n] . V_k   (exact fp32 logit path)
__global__ __launch_bounds__(256) void propagate(
    const uint2* __restrict__ csr, const int* __restrict__ offs,
    const float* __restrict__ A, const float* __restrict__ Bsub,
    float* __restrict__ C, float alpha, int N,
    const float* __restrict__ Vk, float* __restrict__ logits)
{
    int node = blockIdx.x * 4 + (threadIdx.x >> 6);
    int lane = threadIdx.x & 63;
    if (node >= N) return;
    int beg = offs[node], end = offs[node + 1];
    float sx = 0.f, sy = 0.f;
    int j = beg;
    for (; j + 3 < end; j += 4) {     // 4-deep MLP: independent gathers in flight
        uint2 e0 = csr[j], e1 = csr[j + 1], e2 = csr[j + 2], e3 = csr[j + 3];
        float2 v0 = ((const float2*)(A + (size_t)e0.x * 128))[lane];
        float2 v1 = ((const float2*)(A + (size_t)e1.x * 128))[lane];
        float2 v2 = ((const float2*)(A + (size_t)e2.x * 128))[lane];
        float2 v3 = ((const float2*)(A + (size_t)e3.x * 128))[lane];
        float w0 = __uint_as_float(e0.y), w1 = __uint_as_float(e1.y);
        float w2 = __uint_as_float(e2.y), w3 = __uint_as_float(e3.y);
        sx += w0 * v0.x + w1 * v1.x + w2 * v2.x + w3 * v3.x;
        sy += w0 * v0.y + w1 * v1.y + w2 * v2.y + w3 * v3.y;
    }
    for (; j < end; ++j) {
        uint2 e = csr[j];
        float2 v = ((const float2*)(A + (size_t)e.x * 128))[lane];
        float wv = __uint_as_float(e.y);
        sx += wv * v.x; sy += wv * v.y;
    }
    float ox, oy;
    if (Bsub) {
        float2 b = ((const float2*)(Bsub + (size_t)node * 128))[lane];
        ox = alpha * sx - b.x;
        oy = alpha * sy - b.y;
    } else {
        ox = alpha * sx;
        oy = alpha * sy;
    }
    ((float2*)(C + (size_t)node * 128))[lane] = make_float2(ox, oy);

    // fused logit accumulation
    int cc = lane * 2;
    float4 va = *(const float4*)(Vk + 4 * cc);
    float4 vb = *(const float4*)(Vk + 4 * cc + 4);
    float l0 = ox * va.x + oy * vb.x;
    float l1 = ox * va.y + oy * vb.y;
    float l2 = ox * va.z + oy * vb.z;
    float l3 = ox * va.w + oy * vb.w;
#pragma unroll
    for (int off = 32; off; off >>= 1) {
        l0 += __shfl_xor(l0, off); l1 += __shfl_xor(l1, off);
        l2 += __shfl_xor(l2, off); l3 += __shfl_xor(l3, off);
    }
    if (lane == 0) {
        float4 cur = *(const float4*)(logits + 4 * node);
        cur.x += l0; cur.y += l1; cur.z += l2; cur.w += l3;
        *(float4*)(logits + 4 * node) = cur;
    }
}

// ------------------------------------------------- MFMA grouped GEMM-accumulate
// acc_f (+)= sum_{kl=0..4} bf16(T_{5g+kl}) @ bf16(W_f[5g+kl]),  f = g + blockIdx.y
// block: 128 rows x 128 cols, 4 waves in 2x2; wave = 4x4 tiles of 16x16x32 MFMA.
// LDS stride 72 bf16 (144 B): row step = 36 dwords = 4 mod 32 -> <=2-way (free).
__global__ __launch_bounds__(256) void gemm_mfma(
    const float* __restrict__ x, const float* __restrict__ slots,
    const unsigned short* __restrict__ wht, float* __restrict__ acc_base,
    int N, int g)
{
    __shared__ __align__(16) unsigned short Th[128 * 72];
    __shared__ __align__(16) unsigned short Wh[128 * 72];
    int f = g + blockIdx.y;
    int gk0 = (5 * f * (f + 1)) / 2 + 5 * g;
    float* __restrict__ acc = acc_base + (size_t)f * N * 128;
    int r0 = blockIdx.x * 128;
    int tid = threadIdx.x;
    int wave = tid >> 6, lane = tid & 63;
    int wm = (wave >> 1) * 64, wn = (wave & 1) * 64;
    int quad = lane >> 4, l16 = lane & 15;
    size_t matf = (size_t)N * 128;

    f32x4 dacc[4][4];
#pragma unroll
    for (int a = 0; a < 4; ++a)
#pragma unroll
        for (int b = 0; b < 4; ++b)
#pragma unroll
            for (int e = 0; e < 4; ++e) dacc[a][b][e] = 0.f;

    for (int i = 0; i < 10; ++i) {        // K = 640 in steps of 64
        int kl = i >> 1, koff = (i & 1) * 64;
        const float* __restrict__ T = (g == 0 && kl == 0) ? x : slots + (size_t)kl * matf;
        const unsigned short* __restrict__ Wsrc = wht + (size_t)(gk0 + kl) * 16384;
        if (i) __syncthreads();
        // stage T: 128 rows x 64 k (fp32 -> bf16)
#pragma unroll
        for (int jj = 0; jj < 8; ++jj) {
            int chunk = tid + jj * 256;            // 2048 float4 chunks
            int r = chunk >> 4, cp = (chunk & 15) * 4;
            int row = r0 + r;
            float4 v = make_float4(0.f, 0.f, 0.f, 0.f);
            if (row < N) v = *(const float4*)(T + (size_t)row * 128 + koff + cp);
            unsigned u0 = (unsigned)f2bf(v.x) | ((unsigned)f2bf(v.y) << 16);
            unsigned u1 = (unsigned)f2bf(v.z) | ((unsigned)f2bf(v.w) << 16);
            *(uint2*)(&Th[r * 72 + cp]) = make_uint2(u0, u1);
        }
        // stage W^T: 128 n-rows x 64 k (already bf16, already transposed)
#pragma unroll
        for (int jj = 0; jj < 4; ++jj) {
            int chunk = tid + jj * 256;            // 1024 chunks of 8 bf16
            int o = chunk >> 3, cp = (chunk & 7) * 8;
            uint4 v = *(const uint4*)(Wsrc + (size_t)o * 128 + koff + cp);
            *(uint4*)(&Wh[o * 72 + cp]) = v;
        }
        __syncthreads();
#pragma unroll
        for (int ks = 0; ks < 64; ks += 32) {
            short8 av[4], bv[4];
#pragma unroll
            for (int mt = 0; mt < 4; ++mt)
                av[mt] = *(const short8*)(&Th[(wm + mt * 16 + l16) * 72 + ks + quad * 8]);
#pragma unroll
            for (int nt = 0; nt < 4; ++nt)
                bv[nt] = *(const short8*)(&Wh[(wn + nt * 16 + l16) * 72 + ks + quad * 8]);
#pragma unroll
            for (int mt = 0; mt < 4; ++mt)
#pragma unroll
                for (int nt = 0; nt < 4; ++nt)
                    dacc[mt][nt] = __builtin_amdgcn_mfma_f32_16x16x32_bf16(
                        av[mt], bv[nt], dacc[mt][nt], 0, 0, 0);
        }
    }
    // epilogue: C/D layout col=lane&15, row=quad*4+reg  [m89/m91]
#pragma unroll
    for (int mt = 0; mt < 4; ++mt) {
#pragma unroll
        for (int nt = 0; nt < 4; ++nt) {
            int col = wn + nt * 16 + l16;
#pragma unroll
            for (int e = 0; e < 4; ++e) {
                int row = r0 + wm + mt * 16 + quad * 4 + e;
                if (row < N) {
                    float* p = acc + (size_t)row * 128 + col;
                    float v = dacc[mt][nt][e];
                    if (g > 0) v += *p;
                    *p = v;
                }
            }
        }
    }
}

// ------------------------------------------------- attention (precomputed logits) + LN
__global__ __launch_bounds__(256) void attn_ln(
    const float* __restrict__ acc_base, const float* __restrict__ cheb_b,
    const float* __restrict__ logits,
    const float* __restrict__ ln_g, const float* __restrict__ ln_b,
    float* __restrict__ out, int N)
{
    int node = blockIdx.x * 4 + (threadIdx.x >> 6);
    int lane = threadIdx.x & 63;
    if (node >= N) return;
    int c = lane * 2;
    size_t matf = (size_t)N * 128;

    float4 lg = *(const float4*)(logits + 4 * node);
    float m = fmaxf(fmaxf(lg.x, lg.y), fmaxf(lg.z, lg.w));
    float e0 = expf(lg.x - m), e1 = expf(lg.y - m), e2 = expf(lg.z - m), e3 = expf(lg.w - m);
    float inv_s = 1.f / (e0 + e1 + e2 + e3);
    float p[4] = {e0 * inv_s, e1 * inv_s, e2 * inv_s, e3 * inv_s};

    float cx = 0.f, cy = 0.f;
#pragma unroll
    for (int ff = 0; ff < NF; ++ff) {
        float2 v = ((const float2*)(acc_base + (size_t)ff * matf + (size_t)node * 128))[lane];
        cx += p[ff] * (v.x + cheb_b[ff * 128 + c]);
        cy += p[ff] * (v.y + cheb_b[ff * 128 + c + 1]);
    }
    float sum = cx + cy;
#pragma unroll
    for (int off = 32; off; off >>= 1) sum += __shfl_xor(sum, off);
    float mu = sum * (1.f / 128.f);
    float dx = cx - mu, dy = cy - mu;

    float M = fmaxf(fabsf(dx), fabsf(dy));
#pragma unroll
    for (int off = 32; off; off >>= 1) M = fmaxf(M, __shfl_xor(M, off));

    float zx, zy, r;
    if (M > 0.f) {
        float inv = 1.f / M;
        zx = dx * inv; zy = dy * inv;
        float v2 = zx * zx + zy * zy;
#pragma unroll
        for (int off = 32; off; off >>= 1) v2 += __shfl_xor(v2, off);
        float var = v2 * (1.f / 128.f);
        r = rsqrtf(var + 1e-5f * inv * inv);   // scale-safe LN (no fp32 overflow)
    } else {
        zx = 0.f; zy = 0.f; r = 0.f;
    }
    out[(size_t)node * 128 + c]     = zx * r * ln_g[c]     + ln_b[c];
    out[(size_t)node * 128 + c + 1] = zy * r * ln_g[c + 1] + ln_b[c + 1];
}

// ---------------------------------------------------------------- launch
extern "C" void kernel_launch(void* const* d_in, const int* in_sizes, int n_in,
                              void* d_out, int out_size, void* d_ws, size_t ws_size,
                              hipStream_t stream) {
    const float* x       = (const float*)d_in[0];
    const int* ei        = (const int*)d_in[1];     // int32 (jax x64-disabled)
    const float* cheb_w  = (const float*)d_in[2];
    const float* cheb_b  = (const float*)d_in[3];
    const float* attn_w  = (const float*)d_in[4];
    const float* attn_b  = (const float*)d_in[5];
    const float* ln_g    = (const float*)d_in[6];
    const float* ln_b    = (const float*)d_in[7];
    float* out = (float*)d_out;

    int N = in_sizes[0] / 128;
    int E = in_sizes[1] / 2;

    char* w = (char*)d_ws;
    auto alloc = [&](size_t bytes) -> void* {
        void* p = (void*)w;
        w += (bytes + 255) & ~(size_t)255;
        return p;
    };
    size_t mat_bytes = (size_t)N * 128 * sizeof(float);
    float* slots = (float*)alloc(5 * mat_bytes);     // T_k fp32, slot k%5
    float* acc   = (float*)alloc(4 * mat_bytes);     // per-filter accumulators
    uint2* csr   = (uint2*)alloc((size_t)E * sizeof(uint2));
    int* offs    = (int*)alloc((size_t)(N + 1) * sizeof(int));
    int* zero3   = (int*)alloc((size_t)3 * N * sizeof(int));
    int* degr = zero3, *cnt = zero3 + N, *cursor = zero3 + 2 * N;
    float* dinv  = (float*)alloc((size_t)N * sizeof(float));
    int* partials = (int*)alloc(1024 * sizeof(int));
    float* logits = (float*)alloc((size_t)N * 4 * sizeof(float));
    float* V      = (float*)alloc(20 * 512 * sizeof(float));
    float* constj = (float*)alloc(256);
    unsigned short* wht = (unsigned short*)alloc((size_t)50 * 16384 * sizeof(unsigned short));
    if ((size_t)(w - (char*)d_ws) > ws_size) return;  // workspace too small

    int eb = (E + 255) / 256;
    int nb = (N + 255) / 256;
    int pb = (N + 3) / 4;
    size_t matf = (size_t)N * 128;

    // graph build
    zero_ints<<<(3 * N + 255) / 256, 256, 0, stream>>>(zero3, 3 * N);
    count_deg<<<eb, 256, 0, stream>>>(ei, degr, cnt, E);
    dinv_k<<<nb, 256, 0, stream>>>(degr, dinv, N);
    scanA<<<nb, 256, 0, stream>>>(cnt, offs, partials, N);
    scanB<<<1, 256, 0, stream>>>(partials, nb);
    scanC<<<nb, 256, 0, stream>>>(offs, partials, N, E);
    fill_csr<<<eb, 256, 0, stream>>>(ei, dinv, offs, cursor, csr, E);

    // weight prep (tiny)
    wtr<<<50, 256, 0, stream>>>(cheb_w, wht);
    vprep<<<20, 128, 0, stream>>>(cheb_w, attn_w, V);
    bias_const<<<1, 64, 0, stream>>>(cheb_b, attn_w, attn_b, constj);
    logit_init<<<pb, 256, 0, stream>>>(x, V, constj, logits, N);

    int rtiles = (N + 127) / 128;
    for (int g = 0; g < 4; ++g) {
        int kbeg = 5 * g + (g == 0 ? 1 : 0);
        int kend = 5 * g + 4;
        for (int k = kbeg; k <= kend; ++k) {
            const float* A = (k == 1) ? x : slots + (size_t)((k - 1) % 5) * matf;
            const float* B = (k == 1) ? nullptr
                            : ((k == 2) ? x : slots + (size_t)((k - 2) % 5) * matf);
            float* C = slots + (size_t)(k % 5) * matf;
            propagate<<<pb, 256, 0, stream>>>(csr, offs, A, B, C,
                                              (k == 1) ? 1.f : 2.f, N,
                                              V + k * 512, logits);
        }
        dim3 grid(rtiles, 4 - g);
        gemm_mfma<<<grid, 256, 0, stream>>>(x, slots, wht, acc, N, g);
    }
    attn_ln<<<pb, 256, 0, stream>>>(acc, cheb_b, logits, ln_g, ln_b, out, N);
}

// Round 5
// 1856.297 us; speedup vs baseline: 1.7748x; 1.0342x over previous
//
#include <hip/hip_runtime.h>

#define IN_C 128
#define NF 4

typedef __attribute__((ext_vector_type(8))) short short8;   // 8 bf16 (4 VGPRs)
typedef __attribute__((ext_vector_type(4))) float f32x4;    // MFMA C/D frag

__device__ __forceinline__ unsigned short f2bf(float v) {   // RNE float->bf16
    unsigned u = __float_as_uint(v);
    return (unsigned short)((u + 0x7fffu + ((u >> 16) & 1u)) >> 16);
}

// ---------------------------------------------------------------- utilities
__global__ void zero_ints(int* p, int n) {
    int i = blockIdx.x * 256 + threadIdx.x;
    if (i < n) p[i] = 0;
}

__global__ void count_deg(const int* __restrict__ ei, int* __restrict__ degr,
                          int* __restrict__ cnt, int E) {
    int e = blockIdx.x * 256 + threadIdx.x;
    if (e >= E) return;
    atomicAdd(&degr[ei[e]], 1);
    atomicAdd(&cnt[ei[E + e]], 1);
}

__global__ void dinv_k(const int* __restrict__ degr, float* __restrict__ dinv, int N) {
    int i = blockIdx.x * 256 + threadIdx.x;
    if (i >= N) return;
    int d = degr[i];
    dinv[i] = (d > 0) ? rsqrtf((float)d) : 0.0f;
}

__global__ void scanA(const int* __restrict__ in, int* __restrict__ outp,
                      int* __restrict__ partials, int n) {
    __shared__ int tmp[256];
    int t = threadIdx.x;
    int gid = blockIdx.x * 256 + t;
    int v = (gid < n) ? in[gid] : 0;
    tmp[t] = v;
    __syncthreads();
    for (int off = 1; off < 256; off <<= 1) {
        int add = (t >= off) ? tmp[t - off] : 0;
        __syncthreads();
        tmp[t] += add;
        __syncthreads();
    }
    if (gid < n) outp[gid] = tmp[t] - v;
    if (t == 255) partials[blockIdx.x] = tmp[255];
}

__global__ void scanB(int* partials, int n) {  // n <= 256
    __shared__ int tmp[256];
    int t = threadIdx.x;
    int v = (t < n) ? partials[t] : 0;
    tmp[t] = v;
    __syncthreads();
    for (int off = 1; off < 256; off <<= 1) {
        int add = (t >= off) ? tmp[t - off] : 0;
        __syncthreads();
        tmp[t] += add;
        __syncthreads();
    }
    if (t < n) partials[t] = tmp[t] - v;
}

__global__ void scanC(int* __restrict__ offs, const int* __restrict__ partials,
                      int n, int total) {
    int gid = blockIdx.x * 256 + threadIdx.x;
    if (gid < n) offs[gid] += partials[blockIdx.x];
    if (gid == 0) offs[n] = total;
}

__global__ void fill_csr(const int* __restrict__ ei, const float* __restrict__ dinv,
                         const int* __restrict__ offs, int* __restrict__ cursor,
                         uint2* __restrict__ csr, int E) {
    int e = blockIdx.x * 256 + threadIdx.x;
    if (e >= E) return;
    int r = ei[e];
    int c = ei[E + e];
    float w = -dinv[r] * dinv[c] - 1.0f;   // lap_w - 1 ; appended self-loops -> 0, dropped
    int pos = offs[c] + atomicAdd(&cursor[c], 1);
    csr[pos] = make_uint2((unsigned)r, __float_as_uint(w));
}

// ------------------------------------------------- one-time weight prep
// wht[gk][o][c] = bf16(cheb_w[gk][c][o])   (transposed for MFMA B-frag reads)
__global__ void wtr(const float* __restrict__ cheb_w, unsigned short* __restrict__ wht) {
    int gk = blockIdx.x;
    const float* src = cheb_w + (size_t)gk * 16384;
    unsigned short* dst = wht + (size_t)gk * 16384;
    for (int j = 0; j < 64; ++j) {
        int idx = threadIdx.x + j * 256;     // 0..16383, coalesced read
        int c = idx >> 7, o = idx & 127;
        dst[o * 128 + c] = f2bf(src[idx]);
    }
}

// V[k][c][j] = sum_{f: K_f > k} sum_o cheb_w[gk(f,k)][c][o] * attn_w[(f*128+o)*4 + j]
__global__ void vprep(const float* __restrict__ cheb_w, const float* __restrict__ attn_w,
                      float* __restrict__ V) {
    int k = blockIdx.x;      // 0..19
    int c = threadIdx.x;     // 0..127
    float s[4] = {0.f, 0.f, 0.f, 0.f};
    for (int f = k / 5; f < 4; ++f) {
        const float* wrow = cheb_w + (size_t)((5 * f * (f + 1)) / 2 + k) * 16384 + c * 128;
        const float* arow = attn_w + (size_t)f * 512;
        for (int o = 0; o < 128; ++o) {
            float wv = wrow[o];
            s[0] += wv * arow[o * 4 + 0];
            s[1] += wv * arow[o * 4 + 1];
            s[2] += wv * arow[o * 4 + 2];
            s[3] += wv * arow[o * 4 + 3];
        }
    }
    float* dst = V + k * 512 + c * 4;
    dst[0] = s[0]; dst[1] = s[1]; dst[2] = s[2]; dst[3] = s[3];
}

// constj[j] = sum_t cheb_b_flat[t] * attn_w[t*4+j] + attn_b[j]
__global__ void bias_const(const float* __restrict__ cheb_b, const float* __restrict__ attn_w,
                           const float* __restrict__ attn_b, float* __restrict__ constj) {
    int j = threadIdx.x;
    if (j >= 4) return;
    float s = attn_b[j];
    for (int t = 0; t < 512; ++t) s += cheb_b[t] * attn_w[t * 4 + j];
    constj[j] = s;
}

// logits[n][:] = x[n] . V_0 + constj ; also writes xb = bf16(x)
__global__ __launch_bounds__(256) void logit_init(
    const float* __restrict__ x, const float* __restrict__ V,
    const float* __restrict__ constj, float* __restrict__ logits,
    unsigned short* __restrict__ xb, int N)
{
    int node = blockIdx.x * 4 + (threadIdx.x >> 6);
    int lane = threadIdx.x & 63;
    if (node >= N) return;
    float2 v = ((const float2*)(x + (size_t)node * 128))[lane];
    int cc = lane * 2;
    // bf16 mirror of x
    unsigned u = (unsigned)f2bf(v.x) | ((unsigned)f2bf(v.y) << 16);
    *(unsigned*)(xb + (size_t)node * 128 + cc) = u;

    float4 va = *(const float4*)(V + 4 * cc);
    float4 vb = *(const float4*)(V + 4 * cc + 4);
    float l0 = v.x * va.x + v.y * vb.x;
    float l1 = v.x * va.y + v.y * vb.y;
    float l2 = v.x * va.z + v.y * vb.z;
    float l3 = v.x * va.w + v.y * vb.w;
#pragma unroll
    for (int off = 32; off; off >>= 1) {
        l0 += __shfl_xor(l0, off); l1 += __shfl_xor(l1, off);
        l2 += __shfl_xor(l2, off); l3 += __shfl_xor(l3, off);
    }
    if (lane == 0) {
        float4 cj = *(const float4*)constj;
        *(float4*)(logits + 4 * node) =
            make_float4(l0 + cj.x, l1 + cj.y, l2 + cj.z, l3 + cj.w);
    }
}

// ------------------------------------------------- propagation: C = alpha*(S A) - B
// wave per node; two 32-lane halves process 2 edges concurrently, float4/lane.
// Writes fp32 C (recurrence) + bf16 Cb (for MFMA GEMM). Fused fp32 logit update.
__global__ __launch_bounds__(256) void propagate(
    const uint2* __restrict__ csr, const int* __restrict__ offs,
    const float* __restrict__ A, const float* __restrict__ Bsub,
    float* __restrict__ C, unsigned short* __restrict__ Cb,
    float alpha, int N,
    const float* __restrict__ Vk, float* __restrict__ logits)
{
    int node = blockIdx.x * 4 + (threadIdx.x >> 6);
    int lane = threadIdx.x & 63;
    if (node >= N) return;
    int half = lane >> 5;            // which edge of the pair
    int cl = (lane & 31) * 4;        // 4 channels per lane
    int beg = offs[node], end = offs[node + 1];

    float4 s = make_float4(0.f, 0.f, 0.f, 0.f);
    for (int j = beg; j < end; j += 8) {
        uint2 e[4];
        float4 v[4];
#pragma unroll
        for (int u = 0; u < 4; ++u) {
            int je = j + 2 * u + half;
            e[u] = (je < end) ? csr[je] : make_uint2(0u, 0u);   // w=0 for pad
        }
#pragma unroll
        for (int u = 0; u < 4; ++u)
            v[u] = *(const float4*)(A + (size_t)e[u].x * 128 + cl);
#pragma unroll
        for (int u = 0; u < 4; ++u) {
            float wv = __uint_as_float(e[u].y);
            s.x += wv * v[u].x; s.y += wv * v[u].y;
            s.z += wv * v[u].z; s.w += wv * v[u].w;
        }
    }
    // combine the two halves (each lane then holds full sum for channels cl..cl+3)
    s.x += __shfl_xor(s.x, 32); s.y += __shfl_xor(s.y, 32);
    s.z += __shfl_xor(s.z, 32); s.w += __shfl_xor(s.w, 32);

    float4 o;
    if (Bsub) {
        float4 b = *(const float4*)(Bsub + (size_t)node * 128 + cl);
        o.x = alpha * s.x - b.x; o.y = alpha * s.y - b.y;
        o.z = alpha * s.z - b.z; o.w = alpha * s.w - b.w;
    } else {
        o.x = alpha * s.x; o.y = alpha * s.y;
        o.z = alpha * s.z; o.w = alpha * s.w;
    }
    if (half == 0) {
        *(float4*)(C + (size_t)node * 128 + cl) = o;
        unsigned u0 = (unsigned)f2bf(o.x) | ((unsigned)f2bf(o.y) << 16);
        unsigned u1 = (unsigned)f2bf(o.z) | ((unsigned)f2bf(o.w) << 16);
        *(uint2*)(Cb + (size_t)node * 128 + cl) = make_uint2(u0, u1);
    }

    // fused fp32 logit accumulation: l_j += sum_c o_c * Vk[c][j]
    float4 w0 = *(const float4*)(Vk + 4 * cl);
    float4 w1 = *(const float4*)(Vk + 4 * (cl + 1));
    float4 w2 = *(const float4*)(Vk + 4 * (cl + 2));
    float4 w3 = *(const float4*)(Vk + 4 * (cl + 3));
    float l0 = o.x * w0.x + o.y * w1.x + o.z * w2.x + o.w * w3.x;
    float l1 = o.x * w0.y + o.y * w1.y + o.z * w2.y + o.w * w3.y;
    float l2 = o.x * w0.z + o.y * w1.z + o.z * w2.z + o.w * w3.z;
    float l3 = o.x * w0.w + o.y * w1.w + o.z * w2.w + o.w * w3.w;
#pragma unroll
    for (int off = 16; off; off >>= 1) {     // reduce within 32-lane half
        l0 += __shfl_xor(l0, off); l1 += __shfl_xor(l1, off);
        l2 += __shfl_xor(l2, off); l3 += __shfl_xor(l3, off);
    }
    if (lane == 0) {
        float4 cur = *(const float4*)(logits + 4 * node);
        cur.x += l0; cur.y += l1; cur.z += l2; cur.w += l3;
        *(float4*)(logits + 4 * node) = cur;
    }
}

// ------------------------------------------------- MFMA grouped GEMM-accumulate
// acc_f (+)= sum_{kl=0..4} Tb_{5g+kl} @ W_f[5g+kl]^T,  f = g + blockIdx.y
// T staged from bf16 mirror (pure copy). LDS stride 72 bf16 -> conflict-light.
__global__ __launch_bounds__(256) void gemm_mfma(
    const unsigned short* __restrict__ xb, const unsigned short* __restrict__ Tb,
    const unsigned short* __restrict__ wht, float* __restrict__ acc_base,
    int N, int g)
{
    __shared__ __align__(16) unsigned short Th[128 * 72];
    __shared__ __align__(16) unsigned short Wh[128 * 72];
    int f = g + blockIdx.y;
    int gk0 = (5 * f * (f + 1)) / 2 + 5 * g;
    float* __restrict__ acc = acc_base + (size_t)f * N * 128;
    int r0 = blockIdx.x * 128;
    int tid = threadIdx.x;
    int wave = tid >> 6, lane = tid & 63;
    int wm = (wave >> 1) * 64, wn = (wave & 1) * 64;
    int quad = lane >> 4, l16 = lane & 15;
    size_t matf = (size_t)N * 128;

    f32x4 dacc[4][4];
#pragma unroll
    for (int a = 0; a < 4; ++a)
#pragma unroll
        for (int b = 0; b < 4; ++b)
#pragma unroll
            for (int e = 0; e < 4; ++e) dacc[a][b][e] = 0.f;

    for (int i = 0; i < 10; ++i) {        // K = 640 in steps of 64
        int kl = i >> 1, koff = (i & 1) * 64;
        const unsigned short* __restrict__ Tsrc =
            (g == 0 && kl == 0) ? xb : Tb + (size_t)kl * matf;
        const unsigned short* __restrict__ Wsrc = wht + (size_t)(gk0 + kl) * 16384;
        if (i) __syncthreads();
        // stage T: 128 rows x 64 k, bf16 copy (1024 uint4 chunks)
#pragma unroll
        for (int jj = 0; jj < 4; ++jj) {
            int chunk = tid + jj * 256;
            int r = chunk >> 3, cp = (chunk & 7) * 8;
            int row = r0 + r;
            uint4 v = make_uint4(0u, 0u, 0u, 0u);
            if (row < N) v = *(const uint4*)(Tsrc + (size_t)row * 128 + koff + cp);
            *(uint4*)(&Th[r * 72 + cp]) = v;
        }
        // stage W^T: 128 n-rows x 64 k (bf16, pre-transposed)
#pragma unroll
        for (int jj = 0; jj < 4; ++jj) {
            int chunk = tid + jj * 256;
            int o = chunk >> 3, cp = (chunk & 7) * 8;
            uint4 v = *(const uint4*)(Wsrc + (size_t)o * 128 + koff + cp);
            *(uint4*)(&Wh[o * 72 + cp]) = v;
        }
        __syncthreads();
#pragma unroll
        for (int ks = 0; ks < 64; ks += 32) {
            short8 av[4], bv[4];
#pragma unroll
            for (int mt = 0; mt < 4; ++mt)
                av[mt] = *(const short8*)(&Th[(wm + mt * 16 + l16) * 72 + ks + quad * 8]);
#pragma unroll
            for (int nt = 0; nt < 4; ++nt)
                bv[nt] = *(const short8*)(&Wh[(wn + nt * 16 + l16) * 72 + ks + quad * 8]);
#pragma unroll
            for (int mt = 0; mt < 4; ++mt)
#pragma unroll
                for (int nt = 0; nt < 4; ++nt)
                    dacc[mt][nt] = __builtin_amdgcn_mfma_f32_16x16x32_bf16(
                        av[mt], bv[nt], dacc[mt][nt], 0, 0, 0);
        }
    }
    // epilogue: C/D layout col=lane&15, row=quad*4+reg  [m89/m91]
#pragma unroll
    for (int mt = 0; mt < 4; ++mt) {
#pragma unroll
        for (int nt = 0; nt < 4; ++nt) {
            int col = wn + nt * 16 + l16;
#pragma unroll
            for (int e = 0; e < 4; ++e) {
                int row = r0 + wm + mt * 16 + quad * 4 + e;
                if (row < N) {
                    float* p = acc + (size_t)row * 128 + col;
                    float v = dacc[mt][nt][e];
                    if (g > 0) v += *p;
                    *p = v;
                }
            }
        }
    }
}

// ------------------------------------------------- attention (precomputed logits) + LN
__global__ __launch_bounds__(256) void attn_ln(
    const float* __restrict__ acc_base, const float* __restrict__ cheb_b,
    const float* __restrict__ logits,
    const float* __restrict__ ln_g, const float* __restrict__ ln_b,
    float* __restrict__ out, int N)
{
    int node = blockIdx.x * 4 + (threadIdx.x >> 6);
    int lane = threadIdx.x & 63;
    if (node >= N) return;
    int c = lane * 2;
    size_t matf = (size_t)N * 128;

    float4 lg = *(const float4*)(logits + 4 * node);
    float m = fmaxf(fmaxf(lg.x, lg.y), fmaxf(lg.z, lg.w));
    float e0 = expf(lg.x - m), e1 = expf(lg.y - m), e2 = expf(lg.z - m), e3 = expf(lg.w - m);
    float inv_s = 1.f / (e0 + e1 + e2 + e3);
    float p[4] = {e0 * inv_s, e1 * inv_s, e2 * inv_s, e3 * inv_s};

    float cx = 0.f, cy = 0.f;
#pragma unroll
    for (int ff = 0; ff < NF; ++ff) {
        float2 v = ((const float2*)(acc_base + (size_t)ff * matf + (size_t)node * 128))[lane];
        cx += p[ff] * (v.x + cheb_b[ff * 128 + c]);
        cy += p[ff] * (v.y + cheb_b[ff * 128 + c + 1]);
    }
    float sum = cx + cy;
#pragma unroll
    for (int off = 32; off; off >>= 1) sum += __shfl_xor(sum, off);
    float mu = sum * (1.f / 128.f);
    float dx = cx - mu, dy = cy - mu;

    float M = fmaxf(fabsf(dx), fabsf(dy));
#pragma unroll
    for (int off = 32; off; off >>= 1) M = fmaxf(M, __shfl_xor(M, off));

    float zx, zy, r;
    if (M > 0.f) {
        float inv = 1.f / M;
        zx = dx * inv; zy = dy * inv;
        float v2 = zx * zx + zy * zy;
#pragma unroll
        for (int off = 32; off; off >>= 1) v2 += __shfl_xor(v2, off);
        float var = v2 * (1.f / 128.f);
        r = rsqrtf(var + 1e-5f * inv * inv);   // scale-safe LN (no fp32 overflow)
    } else {
        zx = 0.f; zy = 0.f; r = 0.f;
    }
    out[(size_t)node * 128 + c]     = zx * r * ln_g[c]     + ln_b[c];
    out[(size_t)node * 128 + c + 1] = zy * r * ln_g[c + 1] + ln_b[c + 1];
}

// ---------------------------------------------------------------- launch
extern "C" void kernel_launch(void* const* d_in, const int* in_sizes, int n_in,
                              void* d_out, int out_size, void* d_ws, size_t ws_size,
                              hipStream_t stream) {
    const float* x       = (const float*)d_in[0];
    const int* ei        = (const int*)d_in[1];     // int32 (jax x64-disabled)
    const float* cheb_w  = (const float*)d_in[2];
    const float* cheb_b  = (const float*)d_in[3];
    const float* attn_w  = (const float*)d_in[4];
    const float* attn_b  = (const float*)d_in[5];
    const float* ln_g    = (const float*)d_in[6];
    const float* ln_b    = (const float*)d_in[7];
    float* out = (float*)d_out;

    int N = in_sizes[0] / 128;
    int E = in_sizes[1] / 2;

    char* w = (char*)d_ws;
    auto alloc = [&](size_t bytes) -> void* {
        void* p = (void*)w;
        w += (bytes + 255) & ~(size_t)255;
        return p;
    };
    size_t matf = (size_t)N * 128;
    size_t mat_bytes = matf * sizeof(float);
    float* slots3 = (float*)alloc(3 * mat_bytes);           // fp32 T, rotating k%3
    float* acc    = (float*)alloc(4 * mat_bytes);           // per-filter accumulators
    unsigned short* Tb = (unsigned short*)alloc(5 * matf * sizeof(unsigned short)); // bf16 T, slot k%5
    unsigned short* xb = (unsigned short*)alloc(matf * sizeof(unsigned short));     // bf16 x
    uint2* csr   = (uint2*)alloc((size_t)E * sizeof(uint2));
    int* offs    = (int*)alloc((size_t)(N + 1) * sizeof(int));
    int* zero3   = (int*)alloc((size_t)3 * N * sizeof(int));
    int* degr = zero3, *cnt = zero3 + N, *cursor = zero3 + 2 * N;
    float* dinv  = (float*)alloc((size_t)N * sizeof(float));
    int* partials = (int*)alloc(1024 * sizeof(int));
    float* logits = (float*)alloc((size_t)N * 4 * sizeof(float));
    float* V      = (float*)alloc(20 * 512 * sizeof(float));
    float* constj = (float*)alloc(256);
    unsigned short* wht = (unsigned short*)alloc((size_t)50 * 16384 * sizeof(unsigned short));
    if ((size_t)(w - (char*)d_ws) > ws_size) return;  // workspace too small

    int eb = (E + 255) / 256;
    int nb = (N + 255) / 256;
    int pb = (N + 3) / 4;

    // graph build
    zero_ints<<<(3 * N + 255) / 256, 256, 0, stream>>>(zero3, 3 * N);
    count_deg<<<eb, 256, 0, stream>>>(ei, degr, cnt, E);
    dinv_k<<<nb, 256, 0, stream>>>(degr, dinv, N);
    scanA<<<nb, 256, 0, stream>>>(cnt, offs, partials, N);
    scanB<<<1, 256, 0, stream>>>(partials, nb);
    scanC<<<nb, 256, 0, stream>>>(offs, partials, N, E);
    fill_csr<<<eb, 256, 0, stream>>>(ei, dinv, offs, cursor, csr, E);

    // weight prep (tiny)
    wtr<<<50, 256, 0, stream>>>(cheb_w, wht);
    vprep<<<20, 128, 0, stream>>>(cheb_w, attn_w, V);
    bias_const<<<1, 64, 0, stream>>>(cheb_b, attn_w, attn_b, constj);
    logit_init<<<pb, 256, 0, stream>>>(x, V, constj, logits, xb, N);

    int rtiles = (N + 127) / 128;
    for (int g = 0; g < 4; ++g) {
        int kbeg = 5 * g + (g == 0 ? 1 : 0);
        int kend = 5 * g + 4;
        for (int k = kbeg; k <= kend; ++k) {
            const float* A = (k == 1) ? x : slots3 + (size_t)((k - 1) % 3) * matf;
            const float* B = (k == 1) ? nullptr
                            : ((k == 2) ? x : slots3 + (size_t)((k - 2) % 3) * matf);
            float* C = slots3 + (size_t)(k % 3) * matf;
            unsigned short* Cb = Tb + (size_t)(k % 5) * matf;
            propagate<<<pb, 256, 0, stream>>>(csr, offs, A, B, C, Cb,
                                              (k == 1) ? 1.f : 2.f, N,
                                              V + k * 512, logits);
        }
        dim3 grid(rtiles, 4 - g);
        gemm_mfma<<<grid, 256, 0, stream>>>(xb, Tb, wht, acc, N, g);
    }
    attn_ln<<<pb, 256, 0, stream>>>(acc, cheb_b, logits, ln_g, ln_b, out, N);
}